// Round 1
// 516.964 us; speedup vs baseline: 1.0087x; 1.0087x over previous
//
#include <hip/hip_runtime.h>
#include <hip/hip_bf16.h>

// ---------------------------------------------------------------------------
// swin_transformer_angular_tan: qkv GEMM -> fused (windowed attention + proj).
// Round 4: latency attack on the fused kernel (was 148.8us, 21.5% occ,
// 11.6% MfmaUtil -> latency-bound).
//   * head-level software pipelining: K/Q/V frag loads double-buffered so
//     head t+1's HBM latency hides under head t's softmax+PV
//   * P^T staging batched per 32-row block: 8x ds_write_b64 + 4x ds_read_b128,
//     2 sync points/head (was 64x ds_write_b16, 8 sync points)
//   * softmax: no max-subtract (logits bounded ~|1.5| for this problem),
//     bias table pre-scaled by log2e, native v_exp_f32 + v_rcp_f32
//   * aout writes packed to ds_write_b64
//   * phase-2 projw/aout loads explicitly double-buffered (ping-pong)
// ONE __syncthreads total. LDS 80KB/block -> still 2 blocks/CU.
// ---------------------------------------------------------------------------

typedef __bf16 bf16_t;
typedef bf16_t bf16x4 __attribute__((ext_vector_type(4)));
typedef bf16_t bf16x8 __attribute__((ext_vector_type(8)));
typedef float  f32x4  __attribute__((ext_vector_type(4)));

#define NWIN   1024
#define NTOK   64
#define DIM    512
#define NHEADS 16
#define HD     32
#define MTOT   (NWIN*NTOK)      // 65536
#define QKVN   (3*DIM)          // 1536
#define SCLG2E 0.25503494f      // (1/sqrt(32)) * log2(e); bias pre-scaled by log2(e)

// ---------------- async global->LDS (16B per lane, wave-uniform LDS base) ---
__device__ __forceinline__ void async_copy16(const void* g, void* lds_generic) {
    __builtin_amdgcn_global_load_lds(
        (__attribute__((address_space(1))) unsigned int*)(unsigned long long)g,
        (__attribute__((address_space(3))) unsigned int*)(unsigned int)(unsigned long long)lds_generic,
        16, 0, 0);
}

// ---------------- fp32 -> bf16 convert (8 elems/thread) ---------------------
__global__ void cvt_f32_bf16(const float* __restrict__ in, bf16_t* __restrict__ out, int n8) {
    int i = blockIdx.x * blockDim.x + threadIdx.x;
    if (i >= n8) return;
    const float4* p = (const float4*)in;
    float4 a = p[2*i], b = p[2*i+1];
    bf16x8 o;
    o[0]=(bf16_t)a.x; o[1]=(bf16_t)a.y; o[2]=(bf16_t)a.z; o[3]=(bf16_t)a.w;
    o[4]=(bf16_t)b.x; o[5]=(bf16_t)b.y; o[6]=(bf16_t)b.z; o[7]=(bf16_t)b.w;
    ((bf16x8*)out)[i] = o;
}

// ---------------- bias table: bias[h][i][j] * log2e, 16 x 64 x 64 -----------
__global__ void bias_kernel(const float* __restrict__ ap, const float* __restrict__ bp,
                            const float* __restrict__ ar, const float* __restrict__ br,
                            const float* __restrict__ theta_max, float* __restrict__ bias) {
    int idx = blockIdx.x * 256 + threadIdx.x;   // 0..65535
    int h  = idx >> 12;
    int ij = idx & 4095;
    int i = ij >> 6, j = ij & 63;
    int ri = i >> 3, ci = i & 7, rj = j >> 3, cj = j & 7;
    int rad = ri - rj, az = ci - cj;              // -7..7
    int idx_r  = rad < 0 ? rad + 15 : rad;        // python % 15
    int idx_az = az  < 0 ? az  + 15 : az;
    float azang = (float)az * 0.19634954084936207f;       // 2*pi/32
    float rang  = (float)rad * (theta_max[0] * (1.0f/32.0f));
    float v = ap[idx_az*NHEADS + h] * cosf(azang) + bp[idx_az*NHEADS + h] * sinf(azang)
            + ar[idx_r *NHEADS + h] * cosf(rang)  + br[idx_r *NHEADS + h] * sinf(rang);
    bias[idx] = v * 1.4426950408889634f;   // pre-scale by log2(e) for exp2 softmax
}

// ---------------- BT-GEMM: C[M,N] = A[M,K] * Bt[N,K]^T + bias[N] ------------
// 128x128 tile, BK=64, 4 waves each 64x64 (4x4 MFMA 16x16x32).
// LDS tiles XOR-swizzled: row r, 16B-chunk cb stored at position cb^(r&7).
template<int OUT_BF16>
__global__ __launch_bounds__(256, 2)
void gemm_bt(const bf16_t* __restrict__ A, const bf16_t* __restrict__ Bt,
             const float* __restrict__ bias, void* __restrict__ C,
             int M, int N, int K, int ntiles) {
    __shared__ bf16_t sA[128*64];
    __shared__ bf16_t sB[128*64];

    int bid = blockIdx.x;
    int bm = bid / ntiles, bn = bid % ntiles;
    int tid = threadIdx.x;
    int w = tid >> 6, lane = tid & 63;
    int quad = lane >> 4, l16 = lane & 15;
    int wm = w >> 1, wn = w & 1;               // 2x2 wave grid

    f32x4 acc[4][4] = {};

    const bf16_t* Abase = A  + (size_t)(bm*128) * K;
    const bf16_t* Bbase = Bt + (size_t)(bn*128) * K;

    for (int k0 = 0; k0 < K; k0 += 64) {
        for (int i = 0; i < 4; ++i) {
            int off = w*4096 + i*1024 + lane*16;  // byte offset in tile
            int r  = off >> 7;                    // row (128B rows)
            int pb = (off >> 4) & 7;              // physical 16B chunk
            int cb = pb ^ (r & 7);                // logical chunk (swizzle)
            async_copy16(Abase + (size_t)r*K + k0 + cb*8, (char*)sA + w*4096 + i*1024);
            async_copy16(Bbase + (size_t)r*K + k0 + cb*8, (char*)sB + w*4096 + i*1024);
        }
        __syncthreads();

        for (int kk = 0; kk < 64; kk += 32) {
            bf16x8 af[4], bf[4];
            for (int mi = 0; mi < 4; ++mi) {
                int r  = wm*64 + mi*16 + l16;
                int cb = (kk >> 3) + quad;
                int pb = cb ^ (r & 7);
                af[mi] = *(const bf16x8*)((const char*)sA + r*128 + pb*16);
            }
            for (int ni = 0; ni < 4; ++ni) {
                int r  = wn*64 + ni*16 + l16;
                int cb = (kk >> 3) + quad;
                int pb = cb ^ (r & 7);
                bf[ni] = *(const bf16x8*)((const char*)sB + r*128 + pb*16);
            }
            for (int mi = 0; mi < 4; ++mi)
                for (int ni = 0; ni < 4; ++ni)
                    acc[mi][ni] = __builtin_amdgcn_mfma_f32_16x16x32_bf16(
                        af[mi], bf[ni], acc[mi][ni], 0, 0, 0);
        }
        __syncthreads();
    }

    for (int ni = 0; ni < 4; ++ni) {
        int col = bn*128 + wn*64 + ni*16 + l16;
        float bv = bias[col];
        for (int mi = 0; mi < 4; ++mi) {
            int row0 = bm*128 + wm*64 + mi*16 + quad*4;
            f32x4 a = acc[mi][ni];
            for (int reg = 0; reg < 4; ++reg) {
                float v = a[reg] + bv;
                size_t o = (size_t)(row0 + reg) * N + col;
                if (OUT_BF16) ((bf16_t*)C)[o] = (bf16_t)v;
                else          ((float*)C)[o]  = v;
            }
        }
    }
}

// ---------------- fused attention + proj: one block per window --------------
__global__ __launch_bounds__(256, 2)
void attn_proj_kernel(const bf16_t* __restrict__ qkv, const float* __restrict__ bias,
                      const bf16_t* __restrict__ projw, const float* __restrict__ projb,
                      float* __restrict__ out) {
    // aout in proj-A-frag order: frag (mi, h) at (mi*16+h)*512, 512 bf16 = 1KB.
    // Lane L of frag holds A[m = L&15][k = (L>>4)*8 + e] (k = c - h*32).
    __shared__ bf16_t aout[32768];    // 64KB
    __shared__ bf16_t pbuf[4][2048];  // per-wave P^T staging, 4KB each (one 32-row block, 4 frags)

    int b = blockIdx.x;
    int tid = threadIdx.x;
    int w = tid >> 6, lane = tid & 63, quad = lane >> 4, l16 = lane & 15;
    int qh = quad >> 1, ql = quad & 1;
    const bf16_t* base = qkv + (size_t)(b*64) * QKVN;
    f32x4 zero = {0.f, 0.f, 0.f, 0.f};
    bf16_t* pb = pbuf[w];

    // ---- per-head fragment loads: K rows -> S^T A-frags, Q rows -> B-frags,
    //      V^T A-frags via strided scalar loads (av[dt*2+ks]) ----------------
    auto LOADH = [&](int h, bf16x8* ak, bf16x8* bq, bf16x8* av) {
        #pragma unroll
        for (int jt = 0; jt < 4; ++jt)
            ak[jt] = *(const bf16x8*)(base + (size_t)(jt*16 + l16)*QKVN + 512 + h*32 + quad*8);
        #pragma unroll
        for (int it = 0; it < 4; ++it)
            bq[it] = *(const bf16x8*)(base + (size_t)(it*16 + l16)*QKVN + h*32 + quad*8);
        #pragma unroll
        for (int dt = 0; dt < 2; ++dt)
            #pragma unroll
            for (int ks = 0; ks < 2; ++ks) {
                const bf16_t* vb = base + (size_t)(ks*32 + quad*8)*QKVN + 1024 + h*32 + dt*16 + l16;
                bf16x8 tmp;
                #pragma unroll
                for (int e = 0; e < 8; ++e) tmp[e] = vb[(size_t)e*QKVN];
                av[dt*2+ks] = tmp;
            }
    };

    // ---- one head: S^T = K Q^T (per 32-row block) -> exp2 -> packed P^T
    //      staging -> PV accumulate; then column sums + aout write -----------
    auto DOHEAD = [&](int h, bf16x8* ak, bf16x8* bq, bf16x8* av) {
        const float* bh = bias + h*4096;
        f32x4 accO[2][4];
        float s[4];
        #pragma unroll
        for (int it = 0; it < 4; ++it) { s[it] = 0.f; accO[0][it] = zero; accO[1][it] = zero; }

        #pragma unroll
        for (int ks = 0; ks < 2; ++ks) {
            // bias for rows j = ks*32 .. ks*32+31 (L2-resident; issued early)
            f32x4 bb[2][4];
            #pragma unroll
            for (int jh = 0; jh < 2; ++jh)
                #pragma unroll
                for (int it = 0; it < 4; ++it)
                    bb[jh][it] = *(const f32x4*)(bh + (it*16 + l16)*64 + (ks*2+jh)*16 + quad*4);

            // S^T block: C-frag (jh,it): row j = ks*32+jh*16+quad*4+r, col i = it*16+l16
            f32x4 st[2][4];
            #pragma unroll
            for (int jh = 0; jh < 2; ++jh)
                #pragma unroll
                for (int it = 0; it < 4; ++it)
                    st[jh][it] = __builtin_amdgcn_mfma_f32_16x16x32_bf16(ak[ks*2+jh], bq[it], zero, 0, 0, 0);

            // P = exp2(S^T*SCLG2E + bias)  (no max-subtract: logits bounded ~|1.5|)
            // pack 4 consecutive k-slots -> one ds_write_b64 into B-frag order
            #pragma unroll
            for (int it = 0; it < 4; ++it)
                #pragma unroll
                for (int jh = 0; jh < 2; ++jh) {
                    float e0 = __builtin_amdgcn_exp2f(st[jh][it][0]*SCLG2E + bb[jh][it][0]);
                    float e1 = __builtin_amdgcn_exp2f(st[jh][it][1]*SCLG2E + bb[jh][it][1]);
                    float e2 = __builtin_amdgcn_exp2f(st[jh][it][2]*SCLG2E + bb[jh][it][2]);
                    float e3 = __builtin_amdgcn_exp2f(st[jh][it][3]*SCLG2E + bb[jh][it][3]);
                    s[it] += (e0 + e1) + (e2 + e3);
                    bf16x4 pk4;
                    pk4[0] = (bf16_t)e0; pk4[1] = (bf16_t)e1;
                    pk4[2] = (bf16_t)e2; pk4[3] = (bf16_t)e3;
                    // k_local = jh*16+quad*4+r -> frag elem (2jh+qh)*128 + l16*8 + ql*4 + r
                    *(bf16x4*)(pb + it*512 + (2*jh + qh)*128 + l16*8 + ql*4) = pk4;
                }

            // PV: O^T += V^T[.,ks-block] * P^T[ks-block,.]
            #pragma unroll
            for (int it = 0; it < 4; ++it) {
                bf16x8 bp = ((const bf16x8*)(pb + it*512))[lane];
                accO[0][it] = __builtin_amdgcn_mfma_f32_16x16x32_bf16(av[0*2+ks], bp, accO[0][it], 0, 0, 0);
                accO[1][it] = __builtin_amdgcn_mfma_f32_16x16x32_bf16(av[1*2+ks], bp, accO[1][it], 0, 0, 0);
            }
        }

        // softmax denominators (quad reduce) + rescaled O -> aout (packed b64)
        #pragma unroll
        for (int it = 0; it < 4; ++it) {
            float sv = s[it];
            sv += __shfl_xor(sv, 16);
            sv += __shfl_xor(sv, 32);
            float inv = __builtin_amdgcn_rcpf(sv);
            #pragma unroll
            for (int dt = 0; dt < 2; ++dt) {
                bf16x4 o4;
                #pragma unroll
                for (int r = 0; r < 4; ++r) o4[r] = (bf16_t)(accO[dt][it][r] * inv);
                // d = dt*16+quad*4+r -> frag elem (2dt+qh)*128 + l16*8 + ql*4 + r
                *(bf16x4*)(aout + (it*16 + h)*512 + (2*dt + qh)*128 + l16*8 + ql*4) = o4;
            }
        }
    };

    // ---------------- phase 1: 4 heads/wave, software-pipelined loads -------
    bf16x8 akA[4], bqA[4], avA[4], akB[4], bqB[4], avB[4];
    int h0 = w*4;
    LOADH(h0+0, akA, bqA, avA);
    LOADH(h0+1, akB, bqB, avB);
    DOHEAD(h0+0, akA, bqA, avA);
    LOADH(h0+2, akA, bqA, avA);       // flies under head 1's compute
    DOHEAD(h0+1, akB, bqB, avB);
    LOADH(h0+3, akB, bqB, avB);       // flies under head 2's compute
    DOHEAD(h0+2, akA, bqA, avA);
    DOHEAD(h0+3, akB, bqB, avB);

    __syncthreads();   // the ONE barrier

    // ---------------- phase 2: proj. wave w owns cols w*128..w*128+127 ------
    #pragma unroll 1
    for (int half = 0; half < 2; ++half) {
        f32x4 acc[4][4] = {};
        const bf16_t* wb = projw + (size_t)(w*128 + half*64 + l16)*512 + quad*8;

        bf16x8 af0[4], bw0[4], af1[4], bw1[4];
        auto LD = [&](bf16x8* af, bf16x8* bw, int hk) {
            #pragma unroll
            for (int mi = 0; mi < 4; ++mi)
                af[mi] = ((const bf16x8*)(aout + (mi*16 + hk)*512))[lane];
            #pragma unroll
            for (int ni = 0; ni < 4; ++ni)
                bw[ni] = *(const bf16x8*)(wb + (size_t)(ni*16)*512 + hk*32);
        };
        auto MM = [&](bf16x8* af, bf16x8* bw) {
            #pragma unroll
            for (int mi = 0; mi < 4; ++mi)
                #pragma unroll
                for (int ni = 0; ni < 4; ++ni)
                    acc[mi][ni] = __builtin_amdgcn_mfma_f32_16x16x32_bf16(af[mi], bw[ni], acc[mi][ni], 0, 0, 0);
        };

        LD(af0, bw0, 0);
        #pragma unroll 1
        for (int hk = 0; hk < 16; hk += 2) {
            LD(af1, bw1, hk+1);               // next-K loads overlap MFMAs
            MM(af0, bw0);
            if (hk + 2 < 16) LD(af0, bw0, hk+2);
            MM(af1, bw1);
        }

        #pragma unroll
        for (int ni = 0; ni < 4; ++ni) {
            int col = w*128 + half*64 + ni*16 + l16;
            float bv = projb[col];
            #pragma unroll
            for (int mi = 0; mi < 4; ++mi) {
                int row0 = b*64 + mi*16 + quad*4;
                f32x4 a = acc[mi][ni];
                #pragma unroll
                for (int reg = 0; reg < 4; ++reg)
                    out[(size_t)(row0 + reg)*DIM + col] = a[reg] + bv;
            }
        }
    }
}

// ---------------------------------------------------------------------------
extern "C" void kernel_launch(void* const* d_in, const int* in_sizes, int n_in,
                              void* d_out, int out_size, void* d_ws, size_t ws_size,
                              hipStream_t stream) {
    const float* x      = (const float*)d_in[0];
    const float* theta  = (const float*)d_in[1];
    const float* qkv_w  = (const float*)d_in[2];
    const float* qkv_b  = (const float*)d_in[3];
    const float* proj_w = (const float*)d_in[4];
    const float* proj_b = (const float*)d_in[5];
    const float* a_p    = (const float*)d_in[6];
    const float* b_p    = (const float*)d_in[7];
    const float* a_r    = (const float*)d_in[8];
    const float* b_r    = (const float*)d_in[9];
    float* out = (float*)d_out;

    // workspace layout (all 256B aligned)
    char* ws = (char*)d_ws;
    bf16_t* qkvbuf = (bf16_t*)ws;                                  // 65536*1536 bf16 = 192MB
    bf16_t* xb     = (bf16_t*)(ws + 201326592);                    // 65536*512  bf16 = 64MB
    bf16_t* wqkv   = (bf16_t*)(ws + 201326592 + 67108864);         // 1536*512 bf16
    bf16_t* wproj  = (bf16_t*)(ws + 201326592 + 67108864 + 1572864);
    float*  biasbf = (float*) (ws + 201326592 + 67108864 + 1572864 + 524288);

    // 1) converts
    cvt_f32_bf16<<<(MTOT*DIM/8)/256, 256, 0, stream>>>(x, xb, MTOT*DIM/8);
    cvt_f32_bf16<<<(QKVN*DIM/8)/256, 256, 0, stream>>>(qkv_w, wqkv, QKVN*DIM/8);
    cvt_f32_bf16<<<(DIM*DIM/8)/256, 256, 0, stream>>>(proj_w, wproj, DIM*DIM/8);

    // 2) bias table (layout [h][i][j], pre-scaled by log2e — consumed by attn)
    bias_kernel<<<256, 256, 0, stream>>>(a_p, b_p, a_r, b_r, theta, biasbf);

    // 3) qkv GEMM: M=65536 N=1536 K=512 (bf16 out)
    gemm_bt<1><<<(MTOT/128)*(QKVN/128), 256, 0, stream>>>(xb, wqkv, qkv_b, qkvbuf,
                                                          MTOT, QKVN, DIM, QKVN/128);
    // 4) fused attention + proj (fp32 out)
    attn_proj_kernel<<<NWIN, 256, 0, stream>>>(qkvbuf, biasbf, wproj, proj_b, out);
}